// Round 2
// 207.801 us; speedup vs baseline: 1.0289x; 1.0289x over previous
//
#include <hip/hip_runtime.h>

#define BDIM 8
#define NPTS 4096
#define KNEI 20
#define BN (BDIM*NPTS)        // 32768
#define NKCNT (NPTS*KNEI)     // 81920
#define EPSI 1e-5f
#define SLOPE 0.01f

typedef _Float16 half_t;
typedef __attribute__((ext_vector_type(2))) _Float16 h2v;
typedef __attribute__((ext_vector_type(4))) _Float16 h4v;
typedef __attribute__((ext_vector_type(8))) _Float16 h8v;
typedef __attribute__((ext_vector_type(4))) float f32x4;
typedef __attribute__((ext_vector_type(2))) float f32x2;

__device__ __forceinline__ unsigned long long pack4_f16(const f32x4& a) {
    unsigned p0 = __builtin_bit_cast(unsigned, __builtin_amdgcn_cvt_pkrtz(a[0], a[1]));
    unsigned p1 = __builtin_bit_cast(unsigned, __builtin_amdgcn_cvt_pkrtz(a[2], a[3]));
    return ((unsigned long long)p1 << 32) | p0;
}

// ---------------- K0: u = x*W1a^T, v = x*(W1b-W1a)^T  (f16 out) + W2/W3 -> f16 ----------------
__global__ __launch_bounds__(256) void k0_uv(const float* __restrict__ x,
        const float* __restrict__ W1, const float* __restrict__ W2,
        const float* __restrict__ W3, half_t* __restrict__ u,
        half_t* __restrict__ v, half_t* __restrict__ Wh2,
        half_t* __restrict__ Wh3) {
    int tid = threadIdx.x;
    if (blockIdx.x >= BN / 16) {
        // tail blocks: convert W2 / W3 to f16 once
        const float* src = (blockIdx.x == BN / 16) ? W2 : W3;
        half_t* dst = (blockIdx.x == BN / 16) ? Wh2 : Wh3;
        for (int i = tid; i < 4096; i += 256) dst[i] = (half_t)src[i];
        return;
    }
    __shared__ float wlds[64 * 129];
    __shared__ float xs[16 * 64];
    int m0 = blockIdx.x * 16;
    for (int i = tid; i < 8192; i += 256)
        wlds[(i >> 7) * 129 + (i & 127)] = W1[i];
    for (int i = tid; i < 1024; i += 256)
        xs[i] = x[m0 * 64 + i];
    __syncthreads();
    int o = tid & 63;
    int r0 = tid >> 6;
    float au[4] = {0.f, 0.f, 0.f, 0.f};
    float av[4] = {0.f, 0.f, 0.f, 0.f};
    for (int c = 0; c < 64; ++c) {
        float wa = wlds[o * 129 + c];
        float wb = wlds[o * 129 + 64 + c];
        float wd = wb - wa;
#pragma unroll
        for (int jj = 0; jj < 4; ++jj) {
            float xv = xs[(r0 + jj * 4) * 64 + c];
            au[jj] += xv * wa;
            av[jj] += xv * wd;
        }
    }
#pragma unroll
    for (int jj = 0; jj < 4; ++jj) {
        int m = m0 + r0 + jj * 4;
        u[(size_t)m * 64 + o] = (half_t)au[jj];
        v[(size_t)m * 64 + o] = (half_t)av[jj];
    }
}

// ---------------- K1: stats1 of h1 = u[ind]+v, pure register gather ----------------
__global__ __launch_bounds__(256) void k1_stats1(const half_t* __restrict__ u,
        const half_t* __restrict__ v, const int* __restrict__ ind,
        float* __restrict__ s1) {
    __shared__ float sacc[128];
    int tid = threadIdx.x;
    if (tid < 128) sacc[tid] = 0.f;
    int lane = tid & 63, w = tid >> 6;
    int b = blockIdx.x >> 8;
    int n0 = (blockIdx.x & 255) << 4;
    int p = b * NPTS + n0 + w * 4 + (lane >> 4);   // global point, 16 per block
    int c4 = lane & 15;
    h4v vv = *(const h4v*)(v + (size_t)p * 64 + c4 * 4);
    const int* ip = ind + (size_t)p * 20;
    float s0 = 0, s1v = 0, s2v = 0, s3v = 0, q0 = 0, q1 = 0, q2 = 0, q3 = 0;
#pragma unroll
    for (int r = 0; r < 20; ++r) {
        int idx = ip[r];
        h4v uu = *(const h4v*)(u + (size_t)idx * 64 + c4 * 4);
        h4v h = uu + vv;                     // v_pk_add_f16 x2
        float f0 = h[0], f1 = h[1], f2 = h[2], f3 = h[3];
        s0 += f0; q0 = fmaf(f0, f0, q0);
        s1v += f1; q1 = fmaf(f1, f1, q1);
        s2v += f2; q2 = fmaf(f2, f2, q2);
        s3v += f3; q3 = fmaf(f3, f3, q3);
    }
    __syncthreads();
    atomicAdd(&sacc[c4 * 4 + 0], s0);  atomicAdd(&sacc[c4 * 4 + 1], s1v);
    atomicAdd(&sacc[c4 * 4 + 2], s2v); atomicAdd(&sacc[c4 * 4 + 3], s3v);
    atomicAdd(&sacc[64 + c4 * 4 + 0], q0); atomicAdd(&sacc[64 + c4 * 4 + 1], q1);
    atomicAdd(&sacc[64 + c4 * 4 + 2], q2); atomicAdd(&sacc[64 + c4 * 4 + 3], q3);
    __syncthreads();
    if (tid < 128)
        atomicAdd(&s1[(tid >> 6) * 512 + b * 64 + (tid & 63)], sacc[tid]);
}

// ------ K2: register-gather -> norm1+lrelu -> GEMM2 -> stats2 from accumulators ------
// NO h2 output; h2 is recomputed in K3.
__global__ __launch_bounds__(256, 3) void k2_stats2(const half_t* __restrict__ u,
        const half_t* __restrict__ v, const int* __restrict__ ind,
        const half_t* __restrict__ Wh2, const float* __restrict__ s1,
        float* __restrict__ s2) {
    __shared__ float sacc[128];
    int tid = threadIdx.x;
    if (tid < 128) sacc[tid] = 0.f;
    int lane = tid & 63, w = tid >> 6;
    int l15 = lane & 15, q = lane >> 4;
    int b = blockIdx.x >> 8;
    int n0 = (blockIdx.x & 255) << 4;
    int base = b * NPTS + n0;
    // A-frags: Wh2[m=cout][k=cin], 16B vector loads
    h8v aw[4][2];
#pragma unroll
    for (int mt = 0; mt < 4; ++mt)
#pragma unroll
        for (int kc = 0; kc < 2; ++kc)
            aw[mt][kc] = *(const h8v*)(Wh2 + (mt * 16 + l15) * 64 + kc * 32 + q * 8);
    const float inv = 1.0f / (float)NKCNT;
    h8v r1v[2], m1v[2];
#pragma unroll
    for (int kc = 0; kc < 2; ++kc)
#pragma unroll
        for (int j = 0; j < 8; ++j) {
            int c = kc * 32 + q * 8 + j;
            float mm = s1[b * 64 + c] * inv;
            float va = s1[512 + b * 64 + c] * inv - mm * mm;
            float rs = rsqrtf(va + EPSI);
            r1v[kc][j] = (half_t)rs;
            m1v[kc][j] = (half_t)(-mm * rs);
        }
    int idxs[5];
#pragma unroll
    for (int nt = 0; nt < 5; ++nt)
        idxs[nt] = ind[(size_t)base * 20 + w * 80 + nt * 16 + l15];
    float ss[4][4] = {}, sq[4][4] = {};
#pragma unroll
    for (int nt = 0; nt < 5; ++nt) {
        int row = w * 80 + nt * 16 + l15;
        int p = (row * 3277) >> 16;          // row/20, row<320
        const half_t* up = u + (size_t)idxs[nt] * 64;
        const half_t* vp = v + (size_t)(base + p) * 64;
        h8v bfr[2];
#pragma unroll
        for (int kc = 0; kc < 2; ++kc) {
            h8v uu = *(const h8v*)(up + kc * 32 + q * 8);
            h8v vvv = *(const h8v*)(vp + kc * 32 + q * 8);
            h8v h = uu + vvv;
            h8v t = h * r1v[kc] + m1v[kc];
            bfr[kc] = __builtin_elementwise_max(t, t * (half_t)SLOPE);
        }
#pragma unroll
        for (int mt = 0; mt < 4; ++mt) {
            f32x4 a = {0.f, 0.f, 0.f, 0.f};
            a = __builtin_amdgcn_mfma_f32_16x16x32_f16(aw[mt][0], bfr[0], a, 0, 0, 0);
            a = __builtin_amdgcn_mfma_f32_16x16x32_f16(aw[mt][1], bfr[1], a, 0, 0, 0);
#pragma unroll
            for (int j = 0; j < 4; ++j) {
                ss[mt][j] += a[j];
                sq[mt][j] = fmaf(a[j], a[j], sq[mt][j]);
            }
        }
    }
    // butterfly over the 16 row-lanes (l15), then 1-in-16 lanes push to LDS
#pragma unroll
    for (int m = 1; m < 16; m <<= 1)
#pragma unroll
        for (int mt = 0; mt < 4; ++mt)
#pragma unroll
            for (int j = 0; j < 4; ++j) {
                ss[mt][j] += __shfl_xor(ss[mt][j], m, 64);
                sq[mt][j] += __shfl_xor(sq[mt][j], m, 64);
            }
    __syncthreads();
    if (l15 == 0) {
#pragma unroll
        for (int mt = 0; mt < 4; ++mt)
#pragma unroll
            for (int j = 0; j < 4; ++j) {
                atomicAdd(&sacc[mt * 16 + q * 4 + j], ss[mt][j]);
                atomicAdd(&sacc[64 + mt * 16 + q * 4 + j], sq[mt][j]);
            }
    }
    __syncthreads();
    if (tid < 128)
        atomicAdd(&s2[(tid >> 6) * 512 + b * 64 + (tid & 63)], sacc[tid]);
}

// ------ K3: re-gather -> norm1 -> GEMM2 -> norm2 -> GEMM3 -> max/stats3 -> out ------
__global__ __launch_bounds__(256, 3) void k3_fused(const half_t* __restrict__ u,
        const half_t* __restrict__ v, const int* __restrict__ ind,
        const half_t* __restrict__ Wh2, const half_t* __restrict__ Wh3,
        const float* __restrict__ s1, const float* __restrict__ s2,
        float* __restrict__ s3, float* __restrict__ out) {
    __shared__ __align__(16) unsigned char tile[40960];   // 320 rows x 128 B, XOR-swizzled
    __shared__ float sacc[128];
    int tid = threadIdx.x;
    if (tid < 128) sacc[tid] = 0.f;
    int lane = tid & 63, w = tid >> 6;
    int l15 = lane & 15, q = lane >> 4;
    int b = blockIdx.x >> 8;
    int n0 = (blockIdx.x & 255) << 4;
    int base = b * NPTS + n0;
    const float inv = 1.0f / (float)NKCNT;
    // norm params (f16-packed per k-slice)
    h8v r1v[2], m1v[2], r2v[2], m2v[2];
#pragma unroll
    for (int kc = 0; kc < 2; ++kc)
#pragma unroll
        for (int j = 0; j < 8; ++j) {
            int c = kc * 32 + q * 8 + j;
            float mm = s1[b * 64 + c] * inv;
            float va = s1[512 + b * 64 + c] * inv - mm * mm;
            float rs = rsqrtf(va + EPSI);
            r1v[kc][j] = (half_t)rs;
            m1v[kc][j] = (half_t)(-mm * rs);
            float mm2 = s2[b * 64 + c] * inv;
            float va2 = s2[512 + b * 64 + c] * inv - mm2 * mm2;
            float rs2 = rsqrtf(va2 + EPSI);
            r2v[kc][j] = (half_t)rs2;
            m2v[kc][j] = (half_t)(-mm2 * rs2);
        }
    h8v aw[4][2];
#pragma unroll
    for (int mt = 0; mt < 4; ++mt)
#pragma unroll
        for (int kc = 0; kc < 2; ++kc)
            aw[mt][kc] = *(const h8v*)(Wh2 + (mt * 16 + l15) * 64 + kc * 32 + q * 8);
    int idxs[5];
#pragma unroll
    for (int nt = 0; nt < 5; ++nt)
        idxs[nt] = ind[(size_t)base * 20 + w * 80 + nt * 16 + l15];
    // ---- Phase A: gather -> norm1+lrelu -> GEMM2 -> h2 tile (wave-private rows) ----
#pragma unroll
    for (int nt = 0; nt < 5; ++nt) {
        int row = w * 80 + nt * 16 + l15;
        int p = (row * 3277) >> 16;
        int r7 = row & 7;
        const half_t* up = u + (size_t)idxs[nt] * 64;
        const half_t* vp = v + (size_t)(base + p) * 64;
        h8v bfr[2];
#pragma unroll
        for (int kc = 0; kc < 2; ++kc) {
            h8v uu = *(const h8v*)(up + kc * 32 + q * 8);
            h8v vvv = *(const h8v*)(vp + kc * 32 + q * 8);
            h8v h = uu + vvv;
            h8v t = h * r1v[kc] + m1v[kc];
            bfr[kc] = __builtin_elementwise_max(t, t * (half_t)SLOPE);
        }
#pragma unroll
        for (int mt = 0; mt < 4; ++mt) {
            f32x4 a = {0.f, 0.f, 0.f, 0.f};
            a = __builtin_amdgcn_mfma_f32_16x16x32_f16(aw[mt][0], bfr[0], a, 0, 0, 0);
            a = __builtin_amdgcn_mfma_f32_16x16x32_f16(aw[mt][1], bfr[1], a, 0, 0, 0);
            *(unsigned long long*)(tile + row * 128 +
                (((mt * 2 + (q >> 1)) ^ r7) << 4) + (q & 1) * 8) = pack4_f16(a);
        }
    }
    // ---- Phase B: read own rows back -> norm2+lrelu -> GEMM3 B-frags (same wave, no barrier) ----
    h8v bf2[5][2];
#pragma unroll
    for (int nt = 0; nt < 5; ++nt) {
        int row = w * 80 + nt * 16 + l15;
        int r7 = row & 7;
#pragma unroll
        for (int kc = 0; kc < 2; ++kc) {
            h8v hv = *(const h8v*)(tile + row * 128 + (((kc * 4 + q) ^ r7) << 4));
            h8v t = hv * r2v[kc] + m2v[kc];
            bf2[nt][kc] = __builtin_elementwise_max(t, t * (half_t)SLOPE);
        }
    }
    h8v aw3[4][2];
#pragma unroll
    for (int mt = 0; mt < 4; ++mt)
#pragma unroll
        for (int kc = 0; kc < 2; ++kc)
            aw3[mt][kc] = *(const h8v*)(Wh3 + (mt * 16 + l15) * 64 + kc * 32 + q * 8);
    // ---- Phase C: GEMM3 -> h3 tile (overwrite) + stats3 from accumulators ----
    float ss[4][4] = {}, sq[4][4] = {};
#pragma unroll
    for (int nt = 0; nt < 5; ++nt) {
        int row = w * 80 + nt * 16 + l15;
        int r7 = row & 7;
#pragma unroll
        for (int mt = 0; mt < 4; ++mt) {
            f32x4 a = {0.f, 0.f, 0.f, 0.f};
            a = __builtin_amdgcn_mfma_f32_16x16x32_f16(aw3[mt][0], bf2[nt][0], a, 0, 0, 0);
            a = __builtin_amdgcn_mfma_f32_16x16x32_f16(aw3[mt][1], bf2[nt][1], a, 0, 0, 0);
#pragma unroll
            for (int j = 0; j < 4; ++j) {
                ss[mt][j] += a[j];
                sq[mt][j] = fmaf(a[j], a[j], sq[mt][j]);
            }
            *(unsigned long long*)(tile + row * 128 +
                (((mt * 2 + (q >> 1)) ^ r7) << 4) + (q & 1) * 8) = pack4_f16(a);
        }
    }
    // butterfly over l15 for stats3 (register-only, before the barrier)
#pragma unroll
    for (int m = 1; m < 16; m <<= 1)
#pragma unroll
        for (int mt = 0; mt < 4; ++mt)
#pragma unroll
            for (int j = 0; j < 4; ++j) {
                ss[mt][j] += __shfl_xor(ss[mt][j], m, 64);
                sq[mt][j] += __shfl_xor(sq[mt][j], m, 64);
            }
    __syncthreads();   // h3 tile complete + sacc zero visible
    if (l15 == 0) {
#pragma unroll
        for (int mt = 0; mt < 4; ++mt)
#pragma unroll
            for (int j = 0; j < 4; ++j) {
                atomicAdd(&sacc[mt * 16 + q * 4 + j], ss[mt][j]);
                atomicAdd(&sacc[64 + mt * 16 + q * 4 + j], sq[mt][j]);
            }
    }
    // ---- pre-norm max over k=20 (packed f16 pairs) -> out ----
    {
        int c2 = tid & 31, g = tid >> 5;
#pragma unroll
        for (int pp = 0; pp < 2; ++pp) {
            int p = g * 2 + pp;
            h2v mx = {(half_t)-65504.f, (half_t)-65504.f};
            for (int kk = 0; kk < 20; ++kk) {
                int row = p * 20 + kk;
                unsigned hv = *(const unsigned*)(tile + row * 128 +
                    (((c2 >> 2) ^ (row & 7)) << 4) + (c2 & 3) * 4);
                mx = __builtin_elementwise_max(mx, __builtin_bit_cast(h2v, hv));
            }
            f32x2 o = {(float)mx[0], (float)mx[1]};
            *(f32x2*)(out + (size_t)(base + p) * 64 + c2 * 2) = o;
        }
    }
    __syncthreads();
    if (tid < 128)
        atomicAdd(&s3[(tid >> 6) * 512 + b * 64 + (tid & 63)], sacc[tid]);
}

// ---------------- K4: out = lrelu((out - mean3) * rstd3), in place ----------------
__global__ __launch_bounds__(256) void k4_final(float* __restrict__ out,
        const float* __restrict__ s3) {
    int idx = blockIdx.x * 256 + threadIdx.x;
    int c = idx & 63;
    int b = idx >> 18;
    const float inv = 1.0f / (float)NKCNT;
    float mm = s3[b * 64 + c] * inv;
    float vv = s3[512 + b * 64 + c] * inv - mm * mm;
    float r = rsqrtf(vv + EPSI);
    float val = (out[idx] - mm) * r;
    out[idx] = val >= 0.f ? val : SLOPE * val;
}

extern "C" void kernel_launch(void* const* d_in, const int* in_sizes, int n_in,
                              void* d_out, int out_size, void* d_ws, size_t ws_size,
                              hipStream_t stream) {
    const float* x   = (const float*)d_in[0];
    const int*   ind = (const int*)d_in[1];
    const float* W1  = (const float*)d_in[2];
    const float* W2  = (const float*)d_in[3];
    const float* W3  = (const float*)d_in[4];
    float* out = (float*)d_out;

    half_t* u   = (half_t*)d_ws;                       // [32768][64] f16
    half_t* v   = u + (size_t)BN * 64;                 // [32768][64] f16
    half_t* Wh2 = v + (size_t)BN * 64;                 // [64][64] f16
    half_t* Wh3 = Wh2 + 4096;                          // [64][64] f16
    float* stats = (float*)(Wh3 + 4096);
    float* s1 = stats;          // [2][512]
    float* s2 = stats + 1024;   // [2][512]
    float* s3 = stats + 2048;   // [2][512]

    (void)hipMemsetAsync(stats, 0, 3 * 1024 * sizeof(float), stream);
    k0_uv<<<dim3(BN / 16 + 2), dim3(256), 0, stream>>>(x, W1, W2, W3, u, v, Wh2, Wh3);
    k1_stats1<<<dim3(BN / 16), dim3(256), 0, stream>>>(u, v, ind, s1);
    k2_stats2<<<dim3(BN / 16), dim3(256), 0, stream>>>(u, v, ind, Wh2, s1, s2);
    k3_fused<<<dim3(BN / 16), dim3(256), 0, stream>>>(u, v, ind, Wh2, Wh3, s1, s2, s3, out);
    k4_final<<<dim3(BN * 64 / 256), dim3(256), 0, stream>>>(out, s3);
}

// Round 4
// 185.586 us; speedup vs baseline: 1.1521x; 1.1197x over previous
//
#include <hip/hip_runtime.h>

#define BDIM 8
#define NPTS 4096
#define KNEI 20
#define BN (BDIM*NPTS)        // 32768
#define NKCNT (NPTS*KNEI)     // 81920
#define EPSI 1e-5f
#define SLOPE 0.01f

typedef _Float16 half_t;
typedef __attribute__((ext_vector_type(2))) _Float16 h2v;
typedef __attribute__((ext_vector_type(4))) _Float16 h4v;
typedef __attribute__((ext_vector_type(8))) _Float16 h8v;
typedef __attribute__((ext_vector_type(4))) float f32x4;
typedef __attribute__((ext_vector_type(2))) float f32x2;

__device__ __forceinline__ h2v cvt2(float a, float b) {
    return __builtin_bit_cast(h2v, __builtin_amdgcn_cvt_pkrtz(a, b));
}
__device__ __forceinline__ unsigned long long pack4_f16(const f32x4& a) {
    unsigned p0 = __builtin_bit_cast(unsigned, cvt2(a[0], a[1]));
    unsigned p1 = __builtin_bit_cast(unsigned, cvt2(a[2], a[3]));
    return ((unsigned long long)p1 << 32) | p0;
}

// ---------------- K0: u = x*W1a^T, v = x*(W1b-W1a)^T  (f16 out) + W2/W3 -> f16 ----------------
__global__ __launch_bounds__(256) void k0_uv(const float* __restrict__ x,
        const float* __restrict__ W1, const float* __restrict__ W2,
        const float* __restrict__ W3, half_t* __restrict__ u,
        half_t* __restrict__ v, half_t* __restrict__ Wh2,
        half_t* __restrict__ Wh3) {
    int tid = threadIdx.x;
    if (blockIdx.x >= BN / 16) {
        const float* src = (blockIdx.x == BN / 16) ? W2 : W3;
        half_t* dst = (blockIdx.x == BN / 16) ? Wh2 : Wh3;
        for (int i = tid; i < 4096; i += 256) dst[i] = (half_t)src[i];
        return;
    }
    __shared__ float wlds[64 * 129];
    __shared__ float xs[16 * 64];
    int m0 = blockIdx.x * 16;
    for (int i = tid; i < 8192; i += 256)
        wlds[(i >> 7) * 129 + (i & 127)] = W1[i];
    for (int i = tid; i < 1024; i += 256)
        xs[i] = x[m0 * 64 + i];
    __syncthreads();
    int o = tid & 63;
    int r0 = tid >> 6;
    float au[4] = {0.f, 0.f, 0.f, 0.f};
    float av[4] = {0.f, 0.f, 0.f, 0.f};
    for (int c = 0; c < 64; ++c) {
        float wa = wlds[o * 129 + c];
        float wb = wlds[o * 129 + 64 + c];
        float wd = wb - wa;
#pragma unroll
        for (int jj = 0; jj < 4; ++jj) {
            float xv = xs[(r0 + jj * 4) * 64 + c];
            au[jj] += xv * wa;
            av[jj] += xv * wd;
        }
    }
#pragma unroll
    for (int jj = 0; jj < 4; ++jj) {
        int m = m0 + r0 + jj * 4;
        u[(size_t)m * 64 + o] = (half_t)au[jj];
        v[(size_t)m * 64 + o] = (half_t)av[jj];
    }
}

// ---------------- K1: stats1 of h1 = u[ind]+v, 16B register gather ----------------
__global__ __launch_bounds__(256) void k1_stats1(const half_t* __restrict__ u,
        const half_t* __restrict__ v, const int* __restrict__ ind,
        float* __restrict__ s1) {
    __shared__ float sacc[128];
    int tid = threadIdx.x;
    if (tid < 128) sacc[tid] = 0.f;
    int lane = tid & 63, w = tid >> 6;
    int b = blockIdx.x >> 8;
    int n0 = (blockIdx.x & 255) << 4;
    int p = b * NPTS + n0 + w * 4 + (lane >> 4);
    int rh = (lane >> 3) & 1, c8 = lane & 7;
    h8v vv = *(const h8v*)(v + (size_t)p * 64 + c8 * 8);
    const int* ip = ind + (size_t)p * 20;
    float s[8] = {}, qa[8] = {};
#pragma unroll
    for (int r = 0; r < 10; ++r) {
        int idx = ip[r * 2 + rh];
        h8v uu = *(const h8v*)(u + (size_t)idx * 64 + c8 * 8);
        h8v h = uu + vv;
#pragma unroll
        for (int j = 0; j < 8; ++j) {
            float f = (float)h[j];
            s[j] += f; qa[j] = fmaf(f, f, qa[j]);
        }
    }
    // butterfly over lane bits 3,4,5 (rows/points within wave)
#pragma unroll
    for (int m = 8; m <= 32; m <<= 1)
#pragma unroll
        for (int j = 0; j < 8; ++j) {
            s[j] += __shfl_xor(s[j], m, 64);
            qa[j] += __shfl_xor(qa[j], m, 64);
        }
    __syncthreads();
    if ((lane & 56) == 0) {
#pragma unroll
        for (int j = 0; j < 8; ++j) {
            atomicAdd(&sacc[c8 * 8 + j], s[j]);
            atomicAdd(&sacc[64 + c8 * 8 + j], qa[j]);
        }
    }
    __syncthreads();
    if (tid < 128)
        atomicAdd(&s1[(tid >> 6) * 512 + b * 64 + (tid & 63)], sacc[tid]);
}

// ------ K2: register-gather -> norm1+lrelu -> GEMM2 -> stats2 from accumulators ------
// row mapping: row = w*80 + l15*5 + nt  (lane's 5 rows all belong to point l15>>2)
__global__ __launch_bounds__(256, 4) void k2_stats2(const half_t* __restrict__ u,
        const half_t* __restrict__ v, const int* __restrict__ ind,
        const half_t* __restrict__ Wh2, const float* __restrict__ s1,
        float* __restrict__ s2) {
    __shared__ float sacc[128];
    int tid = threadIdx.x;
    if (tid < 128) sacc[tid] = 0.f;
    int lane = tid & 63, w = tid >> 6;
    int l15 = lane & 15, q = lane >> 4;
    int b = blockIdx.x >> 8;
    int n0 = (blockIdx.x & 255) << 4;
    int base = b * NPTS + n0;
    int base20 = base * 20;
    h8v aw[4][2];
#pragma unroll
    for (int mt = 0; mt < 4; ++mt)
#pragma unroll
        for (int kc = 0; kc < 2; ++kc)
            aw[mt][kc] = *(const h8v*)(Wh2 + (mt * 16 + l15) * 64 + kc * 32 + q * 8);
    const float inv = 1.0f / (float)NKCNT;
    h8v r1v[2], m1v[2];
#pragma unroll
    for (int kc = 0; kc < 2; ++kc)
#pragma unroll
        for (int j = 0; j < 8; ++j) {
            int c = kc * 32 + q * 8 + j;
            float mm = s1[b * 64 + c] * inv;
            float va = s1[512 + b * 64 + c] * inv - mm * mm;
            float rs = rsqrtf(va + EPSI);
            r1v[kc][j] = (half_t)rs;
            m1v[kc][j] = (half_t)(-mm * rs);
        }
    int gp = base + w * 4 + (l15 >> 2);     // the single point this lane's rows map to
    h8v vfr[2];
#pragma unroll
    for (int kc = 0; kc < 2; ++kc)
        vfr[kc] = *(const h8v*)(v + (size_t)gp * 64 + kc * 32 + q * 8);
    int idxs[5];
#pragma unroll
    for (int nt = 0; nt < 5; ++nt)
        idxs[nt] = ind[base20 + w * 80 + l15 * 5 + nt];
    float ss[4][4] = {}, sq[4][4] = {};
#pragma unroll
    for (int nt = 0; nt < 5; ++nt) {
        const half_t* up = u + (size_t)idxs[nt] * 64;
        h8v bfr[2];
#pragma unroll
        for (int kc = 0; kc < 2; ++kc) {
            h8v uu = *(const h8v*)(up + kc * 32 + q * 8);
            h8v h = uu + vfr[kc];
            h8v t = h * r1v[kc] + m1v[kc];
            bfr[kc] = __builtin_elementwise_max(t, t * (half_t)SLOPE);
        }
#pragma unroll
        for (int mt = 0; mt < 4; ++mt) {
            f32x4 a = {0.f, 0.f, 0.f, 0.f};
            a = __builtin_amdgcn_mfma_f32_16x16x32_f16(aw[mt][0], bfr[0], a, 0, 0, 0);
            a = __builtin_amdgcn_mfma_f32_16x16x32_f16(aw[mt][1], bfr[1], a, 0, 0, 0);
#pragma unroll
            for (int j = 0; j < 4; ++j) {
                ss[mt][j] += a[j];
                sq[mt][j] = fmaf(a[j], a[j], sq[mt][j]);
            }
        }
    }
#pragma unroll
    for (int m = 1; m < 16; m <<= 1)
#pragma unroll
        for (int mt = 0; mt < 4; ++mt)
#pragma unroll
            for (int j = 0; j < 4; ++j) {
                ss[mt][j] += __shfl_xor(ss[mt][j], m, 64);
                sq[mt][j] += __shfl_xor(sq[mt][j], m, 64);
            }
    __syncthreads();
    if (l15 == 0) {
#pragma unroll
        for (int mt = 0; mt < 4; ++mt)
#pragma unroll
            for (int j = 0; j < 4; ++j) {
                atomicAdd(&sacc[mt * 16 + q * 4 + j], ss[mt][j]);
                atomicAdd(&sacc[64 + mt * 16 + q * 4 + j], sq[mt][j]);
            }
    }
    __syncthreads();
    if (tid < 128)
        atomicAdd(&s2[(tid >> 6) * 512 + b * 64 + (tid & 63)], sacc[tid]);
}

// ------ K3: re-gather -> norm1 -> GEMM2 -> (wave scratch) -> norm2 -> GEMM3 ->
//            in-register max + stats3 -> out.  No cross-wave tile, no h3 LDS. ------
__global__ __launch_bounds__(256, 4) void k3_fused(const half_t* __restrict__ u,
        const half_t* __restrict__ v, const int* __restrict__ ind,
        const half_t* __restrict__ Wh2, const half_t* __restrict__ Wh3,
        const float* __restrict__ s1, const float* __restrict__ s2,
        float* __restrict__ s3, float* __restrict__ out) {
    __shared__ __align__(16) unsigned char wlds[16384];   // W2 swz [0:8K), W3 swz [8K:16K)
    __shared__ __align__(16) unsigned char scr[16384];    // per-wave 2x2KB dbuf
    __shared__ float sacc[128];
    int tid = threadIdx.x;
    if (tid < 128) sacc[tid] = 0.f;
    int lane = tid & 63, w = tid >> 6;
    int l15 = lane & 15, q = lane >> 4;
    int rw7 = l15 & 7;
    int b = blockIdx.x >> 8;
    int n0 = (blockIdx.x & 255) << 4;
    int base = b * NPTS + n0;
    int base20 = base * 20;
    // stage W2/W3 into LDS with chunk^(row&7) swizzle (bank-optimal frag reads)
    for (int i = tid; i < 512; i += 256) {
        int rw = i >> 3, ch = i & 7;
        *(h8v*)(wlds + rw * 128 + ((ch ^ (rw & 7)) << 4)) =
            *(const h8v*)(Wh2 + rw * 64 + ch * 8);
        *(h8v*)(wlds + 8192 + rw * 128 + ((ch ^ (rw & 7)) << 4)) =
            *(const h8v*)(Wh3 + rw * 64 + ch * 8);
    }
    const float inv = 1.0f / (float)NKCNT;
    h8v r1v[2], m1v[2], r2v[2], m2v[2];
#pragma unroll
    for (int kc = 0; kc < 2; ++kc)
#pragma unroll
        for (int j = 0; j < 8; ++j) {
            int c = kc * 32 + q * 8 + j;
            float mm = s1[b * 64 + c] * inv;
            float va = s1[512 + b * 64 + c] * inv - mm * mm;
            float rs = rsqrtf(va + EPSI);
            r1v[kc][j] = (half_t)rs;
            m1v[kc][j] = (half_t)(-mm * rs);
            float mm2 = s2[b * 64 + c] * inv;
            float va2 = s2[512 + b * 64 + c] * inv - mm2 * mm2;
            float rs2 = rsqrtf(va2 + EPSI);
            r2v[kc][j] = (half_t)rs2;
            m2v[kc][j] = (half_t)(-mm2 * rs2);
        }
    int gp = base + w * 4 + (l15 >> 2);
    h8v vfr[2];
#pragma unroll
    for (int kc = 0; kc < 2; ++kc)
        vfr[kc] = *(const h8v*)(v + (size_t)gp * 64 + kc * 32 + q * 8);
    int idxs[5];
#pragma unroll
    for (int nt = 0; nt < 5; ++nt)
        idxs[nt] = ind[base20 + w * 80 + l15 * 5 + nt];
    __syncthreads();   // wlds staged; sacc zeroed
    // ---- Phase A'B': per nt: gather -> norm1+lrelu -> GEMM2 -> scratch -> norm2+lrelu ----
    h8v bf2[5][2];
#pragma unroll
    for (int nt = 0; nt < 5; ++nt) {
        unsigned char* scrw = scr + w * 4096 + (nt & 1) * 2048;
        const half_t* up = u + (size_t)idxs[nt] * 64;
        h8v bfr[2];
#pragma unroll
        for (int kc = 0; kc < 2; ++kc) {
            h8v uu = *(const h8v*)(up + kc * 32 + q * 8);
            h8v h = uu + vfr[kc];
            h8v t = h * r1v[kc] + m1v[kc];
            bfr[kc] = __builtin_elementwise_max(t, t * (half_t)SLOPE);
        }
#pragma unroll
        for (int mt = 0; mt < 4; ++mt) {
            h8v w0 = *(const h8v*)(wlds + (mt * 16 + l15) * 128 + ((q ^ rw7) << 4));
            h8v w1 = *(const h8v*)(wlds + (mt * 16 + l15) * 128 + (((4 + q) ^ rw7) << 4));
            f32x4 a = {0.f, 0.f, 0.f, 0.f};
            a = __builtin_amdgcn_mfma_f32_16x16x32_f16(w0, bfr[0], a, 0, 0, 0);
            a = __builtin_amdgcn_mfma_f32_16x16x32_f16(w1, bfr[1], a, 0, 0, 0);
            *(unsigned long long*)(scrw + l15 * 128 +
                (((mt * 2 + (q >> 1)) ^ rw7) << 4) + (q & 1) * 8) = pack4_f16(a);
        }
#pragma unroll
        for (int kc = 0; kc < 2; ++kc) {
            h8v hv = *(const h8v*)(scrw + l15 * 128 + (((kc * 4 + q) ^ rw7) << 4));
            h8v t = hv * r2v[kc] + m2v[kc];
            bf2[nt][kc] = __builtin_elementwise_max(t, t * (half_t)SLOPE);
        }
    }
    // ---- Phase C: GEMM3 -> stats3 + in-register max (rows of a lane = one point) ----
    float ss[4][4] = {}, sq[4][4] = {};
    h2v pm[4][2];
#pragma unroll
    for (int mt = 0; mt < 4; ++mt)
#pragma unroll
        for (int r = 0; r < 2; ++r)
            pm[mt][r] = (h2v){(half_t)-65504.f, (half_t)-65504.f};
#pragma unroll
    for (int nt = 0; nt < 5; ++nt) {
#pragma unroll
        for (int mt = 0; mt < 4; ++mt) {
            h8v w0 = *(const h8v*)(wlds + 8192 + (mt * 16 + l15) * 128 + ((q ^ rw7) << 4));
            h8v w1 = *(const h8v*)(wlds + 8192 + (mt * 16 + l15) * 128 + (((4 + q) ^ rw7) << 4));
            f32x4 a = {0.f, 0.f, 0.f, 0.f};
            a = __builtin_amdgcn_mfma_f32_16x16x32_f16(w0, bf2[nt][0], a, 0, 0, 0);
            a = __builtin_amdgcn_mfma_f32_16x16x32_f16(w1, bf2[nt][1], a, 0, 0, 0);
#pragma unroll
            for (int j = 0; j < 4; ++j) {
                ss[mt][j] += a[j];
                sq[mt][j] = fmaf(a[j], a[j], sq[mt][j]);
            }
            h2v p0 = cvt2(a[0], a[1]);
            h2v p1 = cvt2(a[2], a[3]);
            pm[mt][0] = __builtin_elementwise_max(pm[mt][0], p0);
            pm[mt][1] = __builtin_elementwise_max(pm[mt][1], p1);
        }
    }
    // max all-reduce over the 4-lane l15 group (rows of one point)
#pragma unroll
    for (int m = 1; m <= 2; m <<= 1)
#pragma unroll
        for (int mt = 0; mt < 4; ++mt)
#pragma unroll
            for (int r = 0; r < 2; ++r) {
                int t = __shfl_xor(__builtin_bit_cast(int, pm[mt][r]), m, 64);
                pm[mt][r] = __builtin_elementwise_max(pm[mt][r],
                               __builtin_bit_cast(h2v, t));
            }
    // lane (l15&3)==mt writes cout block mt*16+q*4 for point gp
    {
        int ms = l15 & 3;
        h2v sa = ms == 0 ? pm[0][0] : ms == 1 ? pm[1][0] : ms == 2 ? pm[2][0] : pm[3][0];
        h2v sb = ms == 0 ? pm[0][1] : ms == 1 ? pm[1][1] : ms == 2 ? pm[2][1] : pm[3][1];
        f32x4 o = {(float)sa[0], (float)sa[1], (float)sb[0], (float)sb[1]};
        *(f32x4*)(out + (size_t)gp * 64 + ms * 16 + q * 4) = o;
    }
    // stats3 butterfly over l15 then LDS accumulate
#pragma unroll
    for (int m = 1; m < 16; m <<= 1)
#pragma unroll
        for (int mt = 0; mt < 4; ++mt)
#pragma unroll
            for (int j = 0; j < 4; ++j) {
                ss[mt][j] += __shfl_xor(ss[mt][j], m, 64);
                sq[mt][j] += __shfl_xor(sq[mt][j], m, 64);
            }
    if (l15 == 0) {
#pragma unroll
        for (int mt = 0; mt < 4; ++mt)
#pragma unroll
            for (int j = 0; j < 4; ++j) {
                atomicAdd(&sacc[mt * 16 + q * 4 + j], ss[mt][j]);
                atomicAdd(&sacc[64 + mt * 16 + q * 4 + j], sq[mt][j]);
            }
    }
    __syncthreads();
    if (tid < 128)
        atomicAdd(&s3[(tid >> 6) * 512 + b * 64 + (tid & 63)], sacc[tid]);
}

// ---------------- K4: out = lrelu((out - mean3) * rstd3), in place ----------------
__global__ __launch_bounds__(256) void k4_final(float* __restrict__ out,
        const float* __restrict__ s3) {
    int idx = blockIdx.x * 256 + threadIdx.x;
    int c = idx & 63;
    int b = idx >> 18;
    const float inv = 1.0f / (float)NKCNT;
    float mm = s3[b * 64 + c] * inv;
    float vv = s3[512 + b * 64 + c] * inv - mm * mm;
    float r = rsqrtf(vv + EPSI);
    float val = (out[idx] - mm) * r;
    out[idx] = val >= 0.f ? val : SLOPE * val;
}

extern "C" void kernel_launch(void* const* d_in, const int* in_sizes, int n_in,
                              void* d_out, int out_size, void* d_ws, size_t ws_size,
                              hipStream_t stream) {
    const float* x   = (const float*)d_in[0];
    const int*   ind = (const int*)d_in[1];
    const float* W1  = (const float*)d_in[2];
    const float* W2  = (const float*)d_in[3];
    const float* W3  = (const float*)d_in[4];
    float* out = (float*)d_out;

    half_t* u   = (half_t*)d_ws;                       // [32768][64] f16
    half_t* v   = u + (size_t)BN * 64;                 // [32768][64] f16
    half_t* Wh2 = v + (size_t)BN * 64;                 // [64][64] f16
    half_t* Wh3 = Wh2 + 4096;                          // [64][64] f16
    float* stats = (float*)(Wh3 + 4096);
    float* s1 = stats;          // [2][512]
    float* s2 = stats + 1024;   // [2][512]
    float* s3 = stats + 2048;   // [2][512]

    (void)hipMemsetAsync(stats, 0, 3 * 1024 * sizeof(float), stream);
    k0_uv<<<dim3(BN / 16 + 2), dim3(256), 0, stream>>>(x, W1, W2, W3, u, v, Wh2, Wh3);
    k1_stats1<<<dim3(BN / 16), dim3(256), 0, stream>>>(u, v, ind, s1);
    k2_stats2<<<dim3(BN / 16), dim3(256), 0, stream>>>(u, v, ind, Wh2, s1, s2);
    k3_fused<<<dim3(BN / 16), dim3(256), 0, stream>>>(u, v, ind, Wh2, Wh3, s1, s2, s3, out);
    k4_final<<<dim3(BN * 64 / 256), dim3(256), 0, stream>>>(out, s3);
}